// Round 13
// baseline (232.720 us; speedup 1.0000x reference)
//
#include <hip/hip_runtime.h>
#include <hip/hip_bf16.h>
#include <math.h>

// Problem constants (B=1)
#define T_SEQ 4096
#define C_DIM 1024
#define N_HEADS 16
#define HEAD_D 64

typedef __bf16 bf16x8 __attribute__((ext_vector_type(8)));
typedef float f32x4 __attribute__((ext_vector_type(4)));
typedef short short4v __attribute__((ext_vector_type(4)));  // 4 bf16 raw bits

__device__ __forceinline__ unsigned int pack_bf16x2(float lo, float hi) {
  unsigned short a = __builtin_bit_cast(unsigned short, __float2bfloat16(lo));
  unsigned short b = __builtin_bit_cast(unsigned short, __float2bfloat16(hi));
  return (unsigned int)a | ((unsigned int)b << 16);
}

__device__ __forceinline__ unsigned short f2bf(float v) {
  return __builtin_bit_cast(unsigned short, __float2bfloat16(v));
}

// Async global->LDS, 16B per lane, wave-uniform LDS base + lane*16.
__device__ __forceinline__ void load_lds16(const void* g, void* l) {
  __builtin_amdgcn_global_load_lds(
      (const __attribute__((address_space(1))) unsigned int*)g,
      (__attribute__((address_space(3))) unsigned int*)l, 16, 0, 0);
}

#define WAITCNT_VM0 asm volatile("s_waitcnt vmcnt(0)" ::: "memory")
__device__ __forceinline__ void block_barrier() {
  asm volatile("s_barrier" ::: "memory");
}

// ---------------------------------------------------------------------------
// prep: x cast (blocks 0..2047) + w_qkv transpose (2048..2815) + w_out
// transpose (2816..3071) + RoPE cos/sin table (3072..3103). One launch.
// ---------------------------------------------------------------------------
__global__ __launch_bounds__(256) void prep_inputs(
    const float* __restrict__ x, const float* __restrict__ w_qkv,
    const float* __restrict__ w_out, unsigned int* __restrict__ xb,
    unsigned int* __restrict__ wqkvT, unsigned int* __restrict__ woutT,
    float2* __restrict__ cs) {
  __shared__ float tile[64][65];
  const int b = blockIdx.x;
  const int tid = threadIdx.x;

  if (b < 2048) {  // cast x -> bf16, 8 elems/thread
    const int i = b * 256 + tid;
    const float4 a = ((const float4*)x)[2 * i];
    const float4 c = ((const float4*)x)[2 * i + 1];
    uint4 r;
    r.x = pack_bf16x2(a.x, a.y);
    r.y = pack_bf16x2(a.z, a.w);
    r.z = pack_bf16x2(c.x, c.y);
    r.w = pack_bf16x2(c.z, c.w);
    ((uint4*)xb)[i] = r;
    return;
  }

  if (b >= 3072) {  // cos/sin table: cs[t*32+j] = (cos, sin)(t * theta^-2j/64)
    const int bb2 = b - 3072;  // 0..31
#pragma unroll
    for (int i = 0; i < 16; i++) {
      const int idx = bb2 * 4096 + i * 256 + tid;  // 0..131071
      const int t = idx >> 5, j = idx & 31;
      const float inv = powf(10000.0f, -(2.0f * (float)j) / 64.0f);
      float s, c;
      sincosf((float)t * inv, &s, &c);
      cs[idx] = make_float2(c, s);
    }
    return;
  }

  const float* W;
  unsigned int* WT;
  int N, bb;
  if (b < 2816) {
    W = w_qkv; WT = wqkvT; N = 3072; bb = b - 2048;
  } else {
    W = w_out; WT = woutT; N = 1024; bb = b - 2816;
  }
  const int K = 1024;
  const int n0 = (bb % (N / 64)) * 64, k0 = (bb / (N / 64)) * 64;
#pragma unroll
  for (int i = 0; i < 16; i++) {
    const int idx = i * 256 + tid;
    const int r = idx >> 6, c = idx & 63;  // r: k, c: n
    tile[r][c] = W[(size_t)(k0 + r) * N + n0 + c];
  }
  __syncthreads();
#pragma unroll
  for (int i = 0; i < 8; i++) {
    const int idx = i * 256 + tid;
    const int rn = idx >> 5, p = idx & 31;  // rn: n-row, p: k-pair
    WT[((size_t)(n0 + rn) * K + k0) / 2 + p] =
        pack_bf16x2(tile[2 * p][rn], tile[2 * p + 1][rn]);
  }
}

// ---------------------------------------------------------------------------
// qkv projection GEMM, 128x128 tiles, FULLY fused epilogue:
//   Q cols (<1024):      RoPE (fp32, via shfl_xor(1) pair + cs table),
//                        pre-scale 0.125*log2e, bf16 -> Qb[h][t][d]
//   K cols (1024..2047): RoPE, bf16 -> Kb[h][t][d]
//   V cols (>=2048):     packed 4x-bf16 -> Vt[d][t] (free transpose)
// ---------------------------------------------------------------------------
__global__ __launch_bounds__(256) void gemm_qkv_rope(
    const unsigned short* __restrict__ A,   // xb [4096][1024]
    const unsigned short* __restrict__ Bt,  // wqkvT [3072][1024]
    const float2* __restrict__ cs,          // [T][32] (cos, sin)
    unsigned short* __restrict__ Qb,        // bf16 [H][T][64]
    unsigned short* __restrict__ Kb,        // bf16 [H][T][64]
    unsigned short* __restrict__ Vt) {      // bf16 [1024][4096]
  const int K = 1024;
  __shared__ __align__(16) unsigned short As[128 * 32];
  __shared__ __align__(16) unsigned short Bs[128 * 32];
  const int tid = threadIdx.x;
  const int w = tid >> 6, lane = tid & 63;
  const int quad = lane >> 4, l16 = lane & 15;
  const int bm = blockIdx.y * 128, bn = blockIdx.x * 128;
  const int mw = (w & 1) * 64, nw = (w >> 1) * 64;

  f32x4 acc[4][4];
#pragma unroll
  for (int mt = 0; mt < 4; mt++)
#pragma unroll
    for (int nt = 0; nt < 4; nt++) acc[mt][nt] = (f32x4){0.f, 0.f, 0.f, 0.f};

  const int crow = lane >> 2;
  const int cq = lane & 3;
  const unsigned short* Ab = A + (size_t)bm * K;
  const unsigned short* Bb = Bt + (size_t)bn * K;

  for (int k0 = 0; k0 < K; k0 += 32) {
#pragma unroll
    for (int i = 0; i < 2; i++) {
      const int c = w + i * 4;
      const int row = c * 16 + crow;
      load_lds16(Ab + (size_t)row * K + k0 + cq * 8, As + c * 512);
      load_lds16(Bb + (size_t)row * K + k0 + cq * 8, Bs + c * 512);
    }
    __syncthreads();

    bf16x8 af[4], bf[4];
#pragma unroll
    for (int mt = 0; mt < 4; mt++)
      af[mt] = __builtin_bit_cast(
          bf16x8, *(const int4*)(As + (mw + mt * 16 + l16) * 32 + quad * 8));
#pragma unroll
    for (int nt = 0; nt < 4; nt++)
      bf[nt] = __builtin_bit_cast(
          bf16x8, *(const int4*)(Bs + (nw + nt * 16 + l16) * 32 + quad * 8));
#pragma unroll
    for (int mt = 0; mt < 4; mt++)
#pragma unroll
      for (int nt = 0; nt < 4; nt++)
        acc[mt][nt] = __builtin_amdgcn_mfma_f32_16x16x32_bf16(
            af[mt], bf[nt], acc[mt][nt], 0, 0, 0);
    __syncthreads();
  }

  if (bn >= 2048) {  // V block: packed stores to Vt[d_global][t]
#pragma unroll
    for (int mt = 0; mt < 4; mt++)
#pragma unroll
      for (int nt = 0; nt < 4; nt++) {
        const int dg = bn + nw + nt * 16 + l16 - 2048;  // 0..1023
        const int t0 = bm + mw + mt * 16 + quad * 4;
        uint2 pk;
        pk.x = pack_bf16x2(acc[mt][nt][0], acc[mt][nt][1]);
        pk.y = pack_bf16x2(acc[mt][nt][2], acc[mt][nt][3]);
        *(uint2*)(Vt + (size_t)dg * T_SEQ + t0) = pk;
      }
  } else {  // Q/K block: RoPE in fp32, store bf16 to Qb/Kb[h][t][d]
    const bool isQ = (bn < 1024);
    const float qs = isQ ? 0.125f * 1.44269504089f : 1.0f;
    unsigned short* dst = isQ ? Qb : Kb;
    const int fbase = bn - (isQ ? 0 : 1024);
#pragma unroll
    for (int mt = 0; mt < 4; mt++)
#pragma unroll
      for (int nt = 0; nt < 4; nt++) {
        const int f = fbase + nw + nt * 16 + l16;  // 0..1023
        const int h = f >> 6, d = f & 63;
        const int j = d >> 1;
        const float sgn = (d & 1) ? 1.0f : -1.0f;
#pragma unroll
        for (int reg = 0; reg < 4; reg++) {
          const int t = bm + mw + mt * 16 + quad * 4 + reg;
          const float2 cv = cs[t * 32 + j];
          const float own = acc[mt][nt][reg];
          // pair partner (feature d^1) lives in lane^1 (same quad, same t)
          const float part = __shfl_xor(own, 1, 64);
          const float r = (own * cv.x + sgn * part * cv.y) * qs;
          dst[((size_t)h * T_SEQ + t) * HEAD_D + d] = f2bf(r);
        }
      }
  }
}

// ---------------------------------------------------------------------------
// 64x64-tile GEMM, BK=64, XOR-chunk-swizzled LDS. For the out-projection.
// ---------------------------------------------------------------------------
__global__ __launch_bounds__(256) void gemm_bt_bf16_64(
    const unsigned short* __restrict__ A,   // [M][K]
    const unsigned short* __restrict__ Bt,  // [N][K]
    float* __restrict__ C, int M, int N, int K) {
  __shared__ __align__(16) unsigned short As[64 * 64];
  __shared__ __align__(16) unsigned short Bs[64 * 64];
  const int tid = threadIdx.x;
  const int w = tid >> 6, lane = tid & 63;
  const int quad = lane >> 4, l16 = lane & 15;
  const int bm = blockIdx.y * 64, bn = blockIdx.x * 64;
  const int mw = (w & 1) * 32, nw = (w >> 1) * 32;

  f32x4 acc[2][2];
#pragma unroll
  for (int mt = 0; mt < 2; mt++)
#pragma unroll
    for (int nt = 0; nt < 2; nt++) acc[mt][nt] = (f32x4){0.f, 0.f, 0.f, 0.f};

  const unsigned short* Ab = A + (size_t)bm * K;
  const unsigned short* Bb = Bt + (size_t)bn * K;

  const int sr0 = tid >> 3;       // row for issue 0 (0..31)
  const int sc8 = tid & 7;        // chunk-in-row
  const int x7 = l16 & 7;
  const int o0 = (quad ^ x7) * 8;  // k-slice 0 chunk
  const int o1 = o0 ^ 32;          // k-slice 1 chunk

  for (int k0 = 0; k0 < K; k0 += 64) {
#pragma unroll
    for (int i = 0; i < 2; i++) {
      const int r = sr0 + i * 32;
      const int csoff = ((sc8 ^ (r & 7)) * 8);
      load_lds16(Ab + (size_t)r * K + k0 + csoff, As + (i * 256 + (tid & ~63)) * 8);
      load_lds16(Bb + (size_t)r * K + k0 + csoff, Bs + (i * 256 + (tid & ~63)) * 8);
    }
    __syncthreads();

    bf16x8 af[2][2], bf[2][2];
#pragma unroll
    for (int mt = 0; mt < 2; mt++) {
      const unsigned short* ar = As + (mw + mt * 16 + l16) * 64;
      af[mt][0] = __builtin_bit_cast(bf16x8, *(const int4*)(ar + o0));
      af[mt][1] = __builtin_bit_cast(bf16x8, *(const int4*)(ar + o1));
    }
#pragma unroll
    for (int nt = 0; nt < 2; nt++) {
      const unsigned short* br = Bs + (nw + nt * 16 + l16) * 64;
      bf[nt][0] = __builtin_bit_cast(bf16x8, *(const int4*)(br + o0));
      bf[nt][1] = __builtin_bit_cast(bf16x8, *(const int4*)(br + o1));
    }
#pragma unroll
    for (int mt = 0; mt < 2; mt++)
#pragma unroll
      for (int nt = 0; nt < 2; nt++) {
        acc[mt][nt] = __builtin_amdgcn_mfma_f32_16x16x32_bf16(
            af[mt][0], bf[nt][0], acc[mt][nt], 0, 0, 0);
        acc[mt][nt] = __builtin_amdgcn_mfma_f32_16x16x32_bf16(
            af[mt][1], bf[nt][1], acc[mt][nt], 0, 0, 0);
      }
    __syncthreads();
  }

#pragma unroll
  for (int mt = 0; mt < 2; mt++)
#pragma unroll
    for (int nt = 0; nt < 2; nt++)
#pragma unroll
      for (int reg = 0; reg < 4; reg++)
        C[(size_t)(bm + mw + mt * 16 + quad * 4 + reg) * N + bn + nw +
          nt * 16 + l16] = acc[mt][nt][reg];
}

// ---------------------------------------------------------------------------
// Flash attention v8 (EXACT R6 best: attn 77.3us, total 213.0us, VGPR 80).
// KEY-SLICE wave decomposition — slim iterations.
//   Wave w owns KEYS [16w,16w+16) x all 64 q.
//    - QK^T: S^T[16k x 64q] = 8 mfma_16x16x32; K reads = wave's 16 rows
//      only (2 x ds_read_b128).
//    - LAYOUT COINCIDENCE: D of 16x16x32 (row=(lane>>4)*4+reg) == B of
//      16x16x16 (k=(lane>>4)*4+j). So bf16(exp2(sv)) packed IN-LANE is
//      directly the PV B-operand: NO P LDS round-trip at all.
//    - PV: O^T partial via 16 mfma_16x16x16bf16_1k; V reads = 4 x
//      ds_read_b64 (wave's k-slice columns).
//    - lsum partial via ones-A 16x16x16 (4 mfma).
//    - End: one 4-way cross-wave combine of partial O (64x64 f32) + lsum
//      through LDS (aliased over K/V buffers) — once per BLOCK.
//   Protocol: single barrier + vmcnt(0)/iter, K+V double-buffer (loads
//   issued one full iteration ahead; v12 proved depth-2 adds nothing and
//   costs residency). setprio KEPT (R12 A/B: removal = +20us — waves
//   drift into load/MFMA roles after the single barrier, T5's regime).
//   Plain launch_bounds (R7/R9: any waves-per-EU hint clamps + spills).
//   Grid 1024 qmap, LDS 33.8KB -> 4 blocks/CU.
// ---------------------------------------------------------------------------
__global__ __launch_bounds__(256) void attn_mfma(
    const unsigned short* __restrict__ Qb, const unsigned short* __restrict__ Kb,
    const unsigned short* __restrict__ Vt, unsigned short* __restrict__ O) {
  const int b = blockIdx.x;
  const int rep = b >> 8;
  const int jj = b & 255;
  const int h = jj & 15;
  const int u = jj >> 4;
  const int qmap[4] = {u, 63 - u, 16 + u, 47 - u};
  const int qt = qmap[rep];

  const int tid = threadIdx.x;
  const int w = tid >> 6;
  const int lane = tid & 63;
  const int quad = lane >> 4;
  const int l16 = lane & 15;
  const int qb = qt * 64;

  // smem partition: Ks0|Ks1|Vs0|Vs1 (4 x 4096 shorts = 32KB). End-combine
  // aliases a [64][68] f32 view over the same storage (loop finished).
  __shared__ __align__(16) unsigned short smem[16384];
  __shared__ __align__(16) float lsumLDS[4][64];
  unsigned short* Ks0 = smem;
  unsigned short* Ks1 = smem + 4096;
  unsigned short* Vs0 = smem + 8192;
  unsigned short* Vs1 = smem + 12288;

  const unsigned short* Kh = Kb + (size_t)h * T_SEQ * HEAD_D;
  const unsigned short* Vh = Vt + (size_t)h * HEAD_D * T_SEQ;

  // Q B-frags for ALL 4 q-tiles (wave spans all 64 q): B[k=d][n=q]:
  // q = qt*16 + l16, d = quad*8 + j (+32 for ks=1). 32 VGPR.
  bf16x8 bq[4][2];
#pragma unroll
  for (int qtile = 0; qtile < 4; qtile++) {
    const unsigned short* qrow =
        Qb + ((size_t)h * T_SEQ + qb + qtile * 16 + l16) * HEAD_D + quad * 8;
#pragma unroll
    for (int ks = 0; ks < 2; ks++)
      bq[qtile][ks] =
          __builtin_bit_cast(bf16x8, *(const int4*)(qrow + ks * 32));
  }

  short4v aones4;
#pragma unroll
  for (int i = 0; i < 4; i++) aones4[i] = (short)0x3F80;  // bf16 1.0

  f32x4 o[4][4];  // [dt][qt] partial O^T for this wave's key-slice
#pragma unroll
  for (int dt = 0; dt < 4; dt++)
#pragma unroll
    for (int qtile = 0; qtile < 4; qtile++)
      o[dt][qtile] = (f32x4){0.f, 0.f, 0.f, 0.f};
  f32x4 lacc[4];
#pragma unroll
  for (int qtile = 0; qtile < 4; qtile++)
    lacc[qtile] = (f32x4){0.f, 0.f, 0.f, 0.f};

  // ---- hoisted lane-constant LDS read bases ----
  const int x7 = l16 & 7;
  const int krow = 16 * w + l16;          // wave's K row (key) in tile
  const int o0 = (quad ^ x7) * 8;         // d-half 0 chunk (swizzled)
  const int o1 = o0 ^ 32;                 // d-half 1
  const unsigned short* k0a = Ks0 + krow * 64 + o0;
  const unsigned short* k0b = Ks0 + krow * 64 + o1;
  const unsigned short* k1a = Ks1 + krow * 64 + o0;
  const unsigned short* k1b = Ks1 + krow * 64 + o1;
  // V A-frag (16x16x16): lane reads V^T[d = dt*16+l16][k = 16w+quad*4 ..+4]
  // = 8B at logical chunk 2w+(quad>>1), XOR-swizzled by row&7 (= l16&7).
  const int vch = (((2 * w + (quad >> 1)) ^ x7) * 8) + (quad & 1) * 4;
  const unsigned short* v0 = Vs0 + l16 * 64 + vch;  // + dt*1024
  const unsigned short* v1 = Vs1 + l16 * 64 + vch;

  // ---- staging: running global pointers ----
  const int sr = tid >> 3;  // row 0..31 (+32 for second issue)
  const int sc = tid & 7;   // 16B chunk
  const int csoff = (sc ^ (sr & 7)) * 8;
  const unsigned short* kgrun = Kh + (size_t)sr * HEAD_D + csoff;
  const unsigned short* vgrun = Vh + (size_t)sr * T_SEQ + csoff;
  const int ntiles = qb / 64 + 1;

  // prologue: stage V[0] and K[0]
  load_lds16(vgrun, Vs0 + w * 512);
  load_lds16(vgrun + 32 * T_SEQ, Vs0 + (4 + w) * 512);
  vgrun += 64;
  load_lds16(kgrun, Ks0 + w * 512);
  load_lds16(kgrun + 2048, Ks0 + (4 + w) * 512);
  kgrun += 4096;

  for (int it = 0; it < ntiles; it++) {
    const int s0 = it * 64;
    const int cur = it & 1;
    const bool pref = (it + 1 < ntiles);  // block-uniform

    // single sync point: own loads drained, then barrier -> K[it],V[it]
    // from ALL waves are in LDS.
    WAITCNT_VM0;
    block_barrier();

    if (pref) {
      unsigned short* vd = (cur ? Vs0 : Vs1) + w * 512;
      load_lds16(vgrun, vd);
      load_lds16(vgrun + 32 * T_SEQ, vd + 2048);
      vgrun += 64;
      unsigned short* kd = (cur ? Ks0 : Ks1) + w * 512;
      load_lds16(kgrun, kd);
      load_lds16(kgrun + 2048, kd + 2048);
      kgrun += 4096;
    }

    // K A-frags: this wave's 16 keys only (2 x b128)
    const bf16x8 a0 = __builtin_bit_cast(
        bf16x8, *(const int4*)(cur ? k1a : k0a));
    const bf16x8 a1 = __builtin_bit_cast(
        bf16x8, *(const int4*)(cur ? k1b : k0b));

    // S^T[16k x 64q]: D row = key = quad*4+reg, col = q = qt*16+l16.
    f32x4 sv[4];
    __builtin_amdgcn_s_setprio(1);
#pragma unroll
    for (int qtile = 0; qtile < 4; qtile++) {
      f32x4 z = (f32x4){0.f, 0.f, 0.f, 0.f};
      z = __builtin_amdgcn_mfma_f32_16x16x32_bf16(a0, bq[qtile][0], z, 0, 0, 0);
      sv[qtile] =
          __builtin_amdgcn_mfma_f32_16x16x32_bf16(a1, bq[qtile][1], z, 0, 0, 0);
    }
    __builtin_amdgcn_s_setprio(0);

    // causal mask: only the diagonal tile is partial
    if (s0 == qb) {
      const int sgbase = s0 + 16 * w + quad * 4;
#pragma unroll
      for (int qtile = 0; qtile < 4; qtile++) {
        const int qg = qb + qtile * 16 + l16;
#pragma unroll
        for (int reg = 0; reg < 4; reg++)
          if (sgbase + reg > qg) sv[qtile][reg] = -1e30f;
      }
    }

    // p = 2^s, packed IN-LANE: D(16x16x32) layout == B(16x16x16) layout,
    // so bp is directly the PV B-operand. No LDS round-trip.
    short4v bp[4];
#pragma unroll
    for (int qtile = 0; qtile < 4; qtile++) {
      uint2 pk;
      pk.x = pack_bf16x2(exp2f(sv[qtile][0]), exp2f(sv[qtile][1]));
      pk.y = pack_bf16x2(exp2f(sv[qtile][2]), exp2f(sv[qtile][3]));
      bp[qtile] = __builtin_bit_cast(short4v, pk);
    }

    // lsum partial via ones-A: D[m][q] = sum over this wave's 16 keys
#pragma unroll
    for (int qtile = 0; qtile < 4; qtile++)
      lacc[qtile] = __builtin_amdgcn_mfma_f32_16x16x16bf16_1k(
          aones4, bp[qtile], lacc[qtile], 0, 0, 0);

    // O^T partial += V^T[:, k-slice] P^T[k-slice, :]
    const unsigned short* vb = cur ? v1 : v0;
    __builtin_amdgcn_s_setprio(1);
#pragma unroll
    for (int dt = 0; dt < 4; dt++) {
      const short4v av =
          __builtin_bit_cast(short4v, *(const uint2*)(vb + dt * 1024));
#pragma unroll
      for (int qtile = 0; qtile < 4; qtile++)
        o[dt][qtile] = __builtin_amdgcn_mfma_f32_16x16x16bf16_1k(
            av, bp[qtile], o[dt][qtile], 0, 0, 0);
    }
    __builtin_amdgcn_s_setprio(0);
  }

  // ---- end combine (once per block): sum 4 waves' partial O and lsum ----
  // lsum rows are replicated across quad/reg; lane l16 of quad 0 writes.
  if (quad == 0) {
#pragma unroll
    for (int qtile = 0; qtile < 4; qtile++)
      lsumLDS[w][qtile * 16 + l16] = lacc[qtile][0];
  }
  block_barrier();  // all loop LDS reads done; smem reusable; lsum visible

  float* comb = (float*)smem;  // [64 q][68] f32 (padded rows, 17.4KB < 32KB)
#pragma unroll
  for (int ww = 0; ww < 4; ww++) {
    if (w == ww) {
#pragma unroll
      for (int dt = 0; dt < 4; dt++)
#pragma unroll
        for (int qtile = 0; qtile < 4; qtile++) {
          // lane holds (d = dt*16 + quad*4 + reg, q = qtile*16 + l16)
          float* dst = comb + (qtile * 16 + l16) * 68 + dt * 16 + quad * 4;
          if (ww == 0) {
            *(f32x4*)dst = o[dt][qtile];
          } else {
            f32x4 t = *(const f32x4*)dst;
            t += o[dt][qtile];
            *(f32x4*)dst = t;
          }
        }
    }
    block_barrier();
  }

  // read-out: wave w owns q rows [16w,16w+16); lane = row 16w+l16, quad
  // covers d = quad*16 .. +16. Scale by 1/lsum, pack bf16, store.
  const int qloc = 16 * w + l16;
  const float ls = lsumLDS[0][qloc] + lsumLDS[1][qloc] + lsumLDS[2][qloc] +
                   lsumLDS[3][qloc];
  const float invl = 1.0f / ls;
  const float* src = comb + qloc * 68 + quad * 16;
  unsigned short* orow =
      O + (size_t)(qb + qloc) * C_DIM + h * HEAD_D + quad * 16;
#pragma unroll
  for (int j2 = 0; j2 < 4; j2++) {
    const f32x4 t = *(const f32x4*)(src + j2 * 4);
    uint2 pk;
    pk.x = pack_bf16x2(t[0] * invl, t[1] * invl);
    pk.y = pack_bf16x2(t[2] * invl, t[3] * invl);
    *(uint2*)(orow + j2 * 4) = pk;
  }
}

// ---------------------------------------------------------------------------
// Launch (4 kernels: prep -> gemm_qkv_rope -> attn -> gemm_out)
// ---------------------------------------------------------------------------
extern "C" void kernel_launch(void* const* d_in, const int* in_sizes, int n_in,
                              void* d_out, int out_size, void* d_ws,
                              size_t ws_size, hipStream_t stream) {
  const float* x = (const float*)d_in[0];      // [T][C]
  const float* w_qkv = (const float*)d_in[1];  // [C][3C]
  const float* w_out = (const float*)d_in[2];  // [C][C]
  float* out = (float*)d_out;                  // [T][C]

  char* ws = (char*)d_ws;
  // Workspace layout (88 MB peak):
  //   [0, 8MB):   attn_ob bf16 [T][C]
  //   [24,25MB):  cs float2 [T][32] (RoPE cos/sin table)
  //   [48,56MB):  Qb bf16 [H][T][D] (roped, pre-scaled by 0.125*log2e)
  //   [56,64MB):  Kb bf16 [H][T][D] (roped)
  //   [64,72MB):  Vt bf16 [H][D][T]
  //   [72,80MB):  xb bf16 [T][C]
  //   [80,86MB):  wqkvT bf16 [3C][C]
  //   [86,88MB):  woutT bf16 [C][C]
  unsigned short* attn_ob = (unsigned short*)ws;
  float2* cst = (float2*)(ws + (size_t)24 * 1024 * 1024);
  unsigned short* Qb = (unsigned short*)(ws + (size_t)48 * 1024 * 1024);
  unsigned short* Kb = (unsigned short*)(ws + (size_t)56 * 1024 * 1024);
  unsigned short* Vt = (unsigned short*)(ws + (size_t)64 * 1024 * 1024);
  unsigned short* xb = (unsigned short*)(ws + (size_t)72 * 1024 * 1024);
  unsigned short* wqkvT = (unsigned short*)(ws + (size_t)80 * 1024 * 1024);
  unsigned short* woutT = (unsigned short*)(ws + (size_t)86 * 1024 * 1024);

  dim3 blk(256);

  prep_inputs<<<dim3(3104), blk, 0, stream>>>(
      x, w_qkv, w_out, (unsigned int*)xb, (unsigned int*)wqkvT,
      (unsigned int*)woutT, cst);

  gemm_qkv_rope<<<dim3(3072 / 128, T_SEQ / 128), blk, 0, stream>>>(
      xb, wqkvT, cst, Qb, Kb, Vt);

  // flash attention v8: key-slice waves, in-register P, 1024 qmap blocks
  attn_mfma<<<dim3(1024), blk, 0, stream>>>(Qb, Kb, Vt, attn_ob);

  gemm_bt_bf16_64<<<dim3(C_DIM / 64, T_SEQ / 64), blk, 0, stream>>>(
      attn_ob, woutT, out, T_SEQ, C_DIM, C_DIM);
}

// Round 14
// 212.548 us; speedup vs baseline: 1.0949x; 1.0949x over previous
//
#include <hip/hip_runtime.h>
#include <hip/hip_bf16.h>
#include <math.h>

// Problem constants (B=1)
#define T_SEQ 4096
#define C_DIM 1024
#define N_HEADS 16
#define HEAD_D 64

typedef __bf16 bf16x8 __attribute__((ext_vector_type(8)));
typedef float f32x4 __attribute__((ext_vector_type(4)));
typedef short short4v __attribute__((ext_vector_type(4)));  // 4 bf16 raw bits

__device__ __forceinline__ unsigned int pack_bf16x2(float lo, float hi) {
  unsigned short a = __builtin_bit_cast(unsigned short, __float2bfloat16(lo));
  unsigned short b = __builtin_bit_cast(unsigned short, __float2bfloat16(hi));
  return (unsigned int)a | ((unsigned int)b << 16);
}

__device__ __forceinline__ unsigned short f2bf(float v) {
  return __builtin_bit_cast(unsigned short, __float2bfloat16(v));
}

// Async global->LDS, 16B per lane, wave-uniform LDS base + lane*16.
__device__ __forceinline__ void load_lds16(const void* g, void* l) {
  __builtin_amdgcn_global_load_lds(
      (const __attribute__((address_space(1))) unsigned int*)g,
      (__attribute__((address_space(3))) unsigned int*)l, 16, 0, 0);
}

#define WAITCNT_VM0 asm volatile("s_waitcnt vmcnt(0)" ::: "memory")
__device__ __forceinline__ void block_barrier() {
  asm volatile("s_barrier" ::: "memory");
}

// ---------------------------------------------------------------------------
// prep: x cast (blocks 0..2047) + w_qkv transpose (2048..2815) + w_out
// transpose (2816..3071) + RoPE cos/sin table (3072..3103). One launch.
// ---------------------------------------------------------------------------
__global__ __launch_bounds__(256) void prep_inputs(
    const float* __restrict__ x, const float* __restrict__ w_qkv,
    const float* __restrict__ w_out, unsigned int* __restrict__ xb,
    unsigned int* __restrict__ wqkvT, unsigned int* __restrict__ woutT,
    float2* __restrict__ cs) {
  __shared__ float tile[64][65];
  const int b = blockIdx.x;
  const int tid = threadIdx.x;

  if (b < 2048) {  // cast x -> bf16, 8 elems/thread
    const int i = b * 256 + tid;
    const float4 a = ((const float4*)x)[2 * i];
    const float4 c = ((const float4*)x)[2 * i + 1];
    uint4 r;
    r.x = pack_bf16x2(a.x, a.y);
    r.y = pack_bf16x2(a.z, a.w);
    r.z = pack_bf16x2(c.x, c.y);
    r.w = pack_bf16x2(c.z, c.w);
    ((uint4*)xb)[i] = r;
    return;
  }

  if (b >= 3072) {  // cos/sin table: cs[t*32+j] = (cos, sin)(t * theta^-2j/64)
    const int bb2 = b - 3072;  // 0..31
#pragma unroll
    for (int i = 0; i < 16; i++) {
      const int idx = bb2 * 4096 + i * 256 + tid;  // 0..131071
      const int t = idx >> 5, j = idx & 31;
      const float inv = powf(10000.0f, -(2.0f * (float)j) / 64.0f);
      float s, c;
      sincosf((float)t * inv, &s, &c);
      cs[idx] = make_float2(c, s);
    }
    return;
  }

  const float* W;
  unsigned int* WT;
  int N, bb;
  if (b < 2816) {
    W = w_qkv; WT = wqkvT; N = 3072; bb = b - 2048;
  } else {
    W = w_out; WT = woutT; N = 1024; bb = b - 2816;
  }
  const int K = 1024;
  const int n0 = (bb % (N / 64)) * 64, k0 = (bb / (N / 64)) * 64;
#pragma unroll
  for (int i = 0; i < 16; i++) {
    const int idx = i * 256 + tid;
    const int r = idx >> 6, c = idx & 63;  // r: k, c: n
    tile[r][c] = W[(size_t)(k0 + r) * N + n0 + c];
  }
  __syncthreads();
#pragma unroll
  for (int i = 0; i < 8; i++) {
    const int idx = i * 256 + tid;
    const int rn = idx >> 5, p = idx & 31;  // rn: n-row, p: k-pair
    WT[((size_t)(n0 + rn) * K + k0) / 2 + p] =
        pack_bf16x2(tile[2 * p][rn], tile[2 * p + 1][rn]);
  }
}

// ---------------------------------------------------------------------------
// qkv projection GEMM, 128x128 tiles, FULLY fused epilogue:
//   Q cols (<1024):      RoPE (fp32, via shfl_xor(1) pair + cs table),
//                        pre-scale 0.125*log2e, bf16 -> Qb[h][t][d]
//   K cols (1024..2047): RoPE, bf16 -> Kb[h][t][d]
//   V cols (>=2048):     packed 4x-bf16 -> Vt[d][t] (free transpose)
// ---------------------------------------------------------------------------
__global__ __launch_bounds__(256) void gemm_qkv_rope(
    const unsigned short* __restrict__ A,   // xb [4096][1024]
    const unsigned short* __restrict__ Bt,  // wqkvT [3072][1024]
    const float2* __restrict__ cs,          // [T][32] (cos, sin)
    unsigned short* __restrict__ Qb,        // bf16 [H][T][64]
    unsigned short* __restrict__ Kb,        // bf16 [H][T][64]
    unsigned short* __restrict__ Vt) {      // bf16 [1024][4096]
  const int K = 1024;
  __shared__ __align__(16) unsigned short As[128 * 32];
  __shared__ __align__(16) unsigned short Bs[128 * 32];
  const int tid = threadIdx.x;
  const int w = tid >> 6, lane = tid & 63;
  const int quad = lane >> 4, l16 = lane & 15;
  const int bm = blockIdx.y * 128, bn = blockIdx.x * 128;
  const int mw = (w & 1) * 64, nw = (w >> 1) * 64;

  f32x4 acc[4][4];
#pragma unroll
  for (int mt = 0; mt < 4; mt++)
#pragma unroll
    for (int nt = 0; nt < 4; nt++) acc[mt][nt] = (f32x4){0.f, 0.f, 0.f, 0.f};

  const int crow = lane >> 2;
  const int cq = lane & 3;
  const unsigned short* Ab = A + (size_t)bm * K;
  const unsigned short* Bb = Bt + (size_t)bn * K;

  for (int k0 = 0; k0 < K; k0 += 32) {
#pragma unroll
    for (int i = 0; i < 2; i++) {
      const int c = w + i * 4;
      const int row = c * 16 + crow;
      load_lds16(Ab + (size_t)row * K + k0 + cq * 8, As + c * 512);
      load_lds16(Bb + (size_t)row * K + k0 + cq * 8, Bs + c * 512);
    }
    __syncthreads();

    bf16x8 af[4], bf[4];
#pragma unroll
    for (int mt = 0; mt < 4; mt++)
      af[mt] = __builtin_bit_cast(
          bf16x8, *(const int4*)(As + (mw + mt * 16 + l16) * 32 + quad * 8));
#pragma unroll
    for (int nt = 0; nt < 4; nt++)
      bf[nt] = __builtin_bit_cast(
          bf16x8, *(const int4*)(Bs + (nw + nt * 16 + l16) * 32 + quad * 8));
#pragma unroll
    for (int mt = 0; mt < 4; mt++)
#pragma unroll
      for (int nt = 0; nt < 4; nt++)
        acc[mt][nt] = __builtin_amdgcn_mfma_f32_16x16x32_bf16(
            af[mt], bf[nt], acc[mt][nt], 0, 0, 0);
    __syncthreads();
  }

  if (bn >= 2048) {  // V block: packed stores to Vt[d_global][t]
#pragma unroll
    for (int mt = 0; mt < 4; mt++)
#pragma unroll
      for (int nt = 0; nt < 4; nt++) {
        const int dg = bn + nw + nt * 16 + l16 - 2048;  // 0..1023
        const int t0 = bm + mw + mt * 16 + quad * 4;
        uint2 pk;
        pk.x = pack_bf16x2(acc[mt][nt][0], acc[mt][nt][1]);
        pk.y = pack_bf16x2(acc[mt][nt][2], acc[mt][nt][3]);
        *(uint2*)(Vt + (size_t)dg * T_SEQ + t0) = pk;
      }
  } else {  // Q/K block: RoPE in fp32, store bf16 to Qb/Kb[h][t][d]
    const bool isQ = (bn < 1024);
    const float qs = isQ ? 0.125f * 1.44269504089f : 1.0f;
    unsigned short* dst = isQ ? Qb : Kb;
    const int fbase = bn - (isQ ? 0 : 1024);
#pragma unroll
    for (int mt = 0; mt < 4; mt++)
#pragma unroll
      for (int nt = 0; nt < 4; nt++) {
        const int f = fbase + nw + nt * 16 + l16;  // 0..1023
        const int h = f >> 6, d = f & 63;
        const int j = d >> 1;
        const float sgn = (d & 1) ? 1.0f : -1.0f;
#pragma unroll
        for (int reg = 0; reg < 4; reg++) {
          const int t = bm + mw + mt * 16 + quad * 4 + reg;
          const float2 cv = cs[t * 32 + j];
          const float own = acc[mt][nt][reg];
          // pair partner (feature d^1) lives in lane^1 (same quad, same t)
          const float part = __shfl_xor(own, 1, 64);
          const float r = (own * cv.x + sgn * part * cv.y) * qs;
          dst[((size_t)h * T_SEQ + t) * HEAD_D + d] = f2bf(r);
        }
      }
  }
}

// ---------------------------------------------------------------------------
// 64x64-tile GEMM, BK=64, XOR-chunk-swizzled LDS. For the out-projection.
// ---------------------------------------------------------------------------
__global__ __launch_bounds__(256) void gemm_bt_bf16_64(
    const unsigned short* __restrict__ A,   // [M][K]
    const unsigned short* __restrict__ Bt,  // [N][K]
    float* __restrict__ C, int M, int N, int K) {
  __shared__ __align__(16) unsigned short As[64 * 64];
  __shared__ __align__(16) unsigned short Bs[64 * 64];
  const int tid = threadIdx.x;
  const int w = tid >> 6, lane = tid & 63;
  const int quad = lane >> 4, l16 = lane & 15;
  const int bm = blockIdx.y * 64, bn = blockIdx.x * 64;
  const int mw = (w & 1) * 32, nw = (w >> 1) * 32;

  f32x4 acc[2][2];
#pragma unroll
  for (int mt = 0; mt < 2; mt++)
#pragma unroll
    for (int nt = 0; nt < 2; nt++) acc[mt][nt] = (f32x4){0.f, 0.f, 0.f, 0.f};

  const unsigned short* Ab = A + (size_t)bm * K;
  const unsigned short* Bb = Bt + (size_t)bn * K;

  const int sr0 = tid >> 3;       // row for issue 0 (0..31)
  const int sc8 = tid & 7;        // chunk-in-row
  const int x7 = l16 & 7;
  const int o0 = (quad ^ x7) * 8;  // k-slice 0 chunk
  const int o1 = o0 ^ 32;          // k-slice 1 chunk

  for (int k0 = 0; k0 < K; k0 += 64) {
#pragma unroll
    for (int i = 0; i < 2; i++) {
      const int r = sr0 + i * 32;
      const int csoff = ((sc8 ^ (r & 7)) * 8);
      load_lds16(Ab + (size_t)r * K + k0 + csoff, As + (i * 256 + (tid & ~63)) * 8);
      load_lds16(Bb + (size_t)r * K + k0 + csoff, Bs + (i * 256 + (tid & ~63)) * 8);
    }
    __syncthreads();

    bf16x8 af[2][2], bf[2][2];
#pragma unroll
    for (int mt = 0; mt < 2; mt++) {
      const unsigned short* ar = As + (mw + mt * 16 + l16) * 64;
      af[mt][0] = __builtin_bit_cast(bf16x8, *(const int4*)(ar + o0));
      af[mt][1] = __builtin_bit_cast(bf16x8, *(const int4*)(ar + o1));
    }
#pragma unroll
    for (int nt = 0; nt < 2; nt++) {
      const unsigned short* br = Bs + (nw + nt * 16 + l16) * 64;
      bf[nt][0] = __builtin_bit_cast(bf16x8, *(const int4*)(br + o0));
      bf[nt][1] = __builtin_bit_cast(bf16x8, *(const int4*)(br + o1));
    }
#pragma unroll
    for (int mt = 0; mt < 2; mt++)
#pragma unroll
      for (int nt = 0; nt < 2; nt++) {
        acc[mt][nt] = __builtin_amdgcn_mfma_f32_16x16x32_bf16(
            af[mt][0], bf[nt][0], acc[mt][nt], 0, 0, 0);
        acc[mt][nt] = __builtin_amdgcn_mfma_f32_16x16x32_bf16(
            af[mt][1], bf[nt][1], acc[mt][nt], 0, 0, 0);
      }
    __syncthreads();
  }

#pragma unroll
  for (int mt = 0; mt < 2; mt++)
#pragma unroll
    for (int nt = 0; nt < 2; nt++)
#pragma unroll
      for (int reg = 0; reg < 4; reg++)
        C[(size_t)(bm + mw + mt * 16 + quad * 4 + reg) * N + bn + nw +
          nt * 16 + l16] = acc[mt][nt][reg];
}

// ---------------------------------------------------------------------------
// Flash attention v8 (TRUE byte-exact R6 best: attn 77.3us, total 213.0us,
// VGPR 80). R13's "restore" dropped the __launch_bounds__(256,3) — plain
// bounds made the allocator target 96 VGPR and emit a 30-40% slower
// schedule (R12/R13 A/B: plain = 97-109us). (256,3) caps ~170 VGPR (no
// clamp, no spill; FETCH 12.3MB) and is the measured optimum.
// KEY-SLICE wave decomposition — slim iterations.
//   Wave w owns KEYS [16w,16w+16) x all 64 q.
//    - QK^T: S^T[16k x 64q] = 8 mfma_16x16x32; K reads = wave's 16 rows
//      only (2 x ds_read_b128).
//    - LAYOUT COINCIDENCE: D of 16x16x32 (row=(lane>>4)*4+reg) == B of
//      16x16x16 (k=(lane>>4)*4+j). So bf16(exp2(sv)) packed IN-LANE is
//      directly the PV B-operand: NO P LDS round-trip at all.
//    - PV: O^T partial via 16 mfma_16x16x16bf16_1k; V reads = 4 x
//      ds_read_b64 (wave's k-slice columns).
//    - lsum partial via ones-A 16x16x16 (4 mfma).
//    - End: one 4-way cross-wave combine of partial O (64x64 f32) + lsum
//      through LDS (aliased over K/V buffers) — once per BLOCK.
//   Protocol: single barrier + vmcnt(0)/iter, K+V double-buffer (loads
//   issued one full iteration ahead; v12 proved depth-2 adds nothing).
//   setprio KEPT (R12 A/B: removal = +20us). Grid 1024 qmap, LDS 33.8KB.
// ---------------------------------------------------------------------------
__global__ __launch_bounds__(256, 3) void attn_mfma(
    const unsigned short* __restrict__ Qb, const unsigned short* __restrict__ Kb,
    const unsigned short* __restrict__ Vt, unsigned short* __restrict__ O) {
  const int b = blockIdx.x;
  const int rep = b >> 8;
  const int jj = b & 255;
  const int h = jj & 15;
  const int u = jj >> 4;
  const int qmap[4] = {u, 63 - u, 16 + u, 47 - u};
  const int qt = qmap[rep];

  const int tid = threadIdx.x;
  const int w = tid >> 6;
  const int lane = tid & 63;
  const int quad = lane >> 4;
  const int l16 = lane & 15;
  const int qb = qt * 64;

  // smem partition: Ks0|Ks1|Vs0|Vs1 (4 x 4096 shorts = 32KB). End-combine
  // aliases a [64][68] f32 view over the same storage (loop finished).
  __shared__ __align__(16) unsigned short smem[16384];
  __shared__ __align__(16) float lsumLDS[4][64];
  unsigned short* Ks0 = smem;
  unsigned short* Ks1 = smem + 4096;
  unsigned short* Vs0 = smem + 8192;
  unsigned short* Vs1 = smem + 12288;

  const unsigned short* Kh = Kb + (size_t)h * T_SEQ * HEAD_D;
  const unsigned short* Vh = Vt + (size_t)h * HEAD_D * T_SEQ;

  // Q B-frags for ALL 4 q-tiles (wave spans all 64 q): B[k=d][n=q]:
  // q = qt*16 + l16, d = quad*8 + j (+32 for ks=1). 32 VGPR.
  bf16x8 bq[4][2];
#pragma unroll
  for (int qtile = 0; qtile < 4; qtile++) {
    const unsigned short* qrow =
        Qb + ((size_t)h * T_SEQ + qb + qtile * 16 + l16) * HEAD_D + quad * 8;
#pragma unroll
    for (int ks = 0; ks < 2; ks++)
      bq[qtile][ks] =
          __builtin_bit_cast(bf16x8, *(const int4*)(qrow + ks * 32));
  }

  short4v aones4;
#pragma unroll
  for (int i = 0; i < 4; i++) aones4[i] = (short)0x3F80;  // bf16 1.0

  f32x4 o[4][4];  // [dt][qt] partial O^T for this wave's key-slice
#pragma unroll
  for (int dt = 0; dt < 4; dt++)
#pragma unroll
    for (int qtile = 0; qtile < 4; qtile++)
      o[dt][qtile] = (f32x4){0.f, 0.f, 0.f, 0.f};
  f32x4 lacc[4];
#pragma unroll
  for (int qtile = 0; qtile < 4; qtile++)
    lacc[qtile] = (f32x4){0.f, 0.f, 0.f, 0.f};

  // ---- hoisted lane-constant LDS read bases ----
  const int x7 = l16 & 7;
  const int krow = 16 * w + l16;          // wave's K row (key) in tile
  const int o0 = (quad ^ x7) * 8;         // d-half 0 chunk (swizzled)
  const int o1 = o0 ^ 32;                 // d-half 1
  const unsigned short* k0a = Ks0 + krow * 64 + o0;
  const unsigned short* k0b = Ks0 + krow * 64 + o1;
  const unsigned short* k1a = Ks1 + krow * 64 + o0;
  const unsigned short* k1b = Ks1 + krow * 64 + o1;
  // V A-frag (16x16x16): lane reads V^T[d = dt*16+l16][k = 16w+quad*4 ..+4]
  // = 8B at logical chunk 2w+(quad>>1), XOR-swizzled by row&7 (= l16&7).
  const int vch = (((2 * w + (quad >> 1)) ^ x7) * 8) + (quad & 1) * 4;
  const unsigned short* v0 = Vs0 + l16 * 64 + vch;  // + dt*1024
  const unsigned short* v1 = Vs1 + l16 * 64 + vch;

  // ---- staging: running global pointers ----
  const int sr = tid >> 3;  // row 0..31 (+32 for second issue)
  const int sc = tid & 7;   // 16B chunk
  const int csoff = (sc ^ (sr & 7)) * 8;
  const unsigned short* kgrun = Kh + (size_t)sr * HEAD_D + csoff;
  const unsigned short* vgrun = Vh + (size_t)sr * T_SEQ + csoff;
  const int ntiles = qb / 64 + 1;

  // prologue: stage V[0] and K[0]
  load_lds16(vgrun, Vs0 + w * 512);
  load_lds16(vgrun + 32 * T_SEQ, Vs0 + (4 + w) * 512);
  vgrun += 64;
  load_lds16(kgrun, Ks0 + w * 512);
  load_lds16(kgrun + 2048, Ks0 + (4 + w) * 512);
  kgrun += 4096;

  for (int it = 0; it < ntiles; it++) {
    const int s0 = it * 64;
    const int cur = it & 1;
    const bool pref = (it + 1 < ntiles);  // block-uniform

    // single sync point: own loads drained, then barrier -> K[it],V[it]
    // from ALL waves are in LDS.
    WAITCNT_VM0;
    block_barrier();

    if (pref) {
      unsigned short* vd = (cur ? Vs0 : Vs1) + w * 512;
      load_lds16(vgrun, vd);
      load_lds16(vgrun + 32 * T_SEQ, vd + 2048);
      vgrun += 64;
      unsigned short* kd = (cur ? Ks0 : Ks1) + w * 512;
      load_lds16(kgrun, kd);
      load_lds16(kgrun + 2048, kd + 2048);
      kgrun += 4096;
    }

    // K A-frags: this wave's 16 keys only (2 x b128)
    const bf16x8 a0 = __builtin_bit_cast(
        bf16x8, *(const int4*)(cur ? k1a : k0a));
    const bf16x8 a1 = __builtin_bit_cast(
        bf16x8, *(const int4*)(cur ? k1b : k0b));

    // S^T[16k x 64q]: D row = key = quad*4+reg, col = q = qt*16+l16.
    f32x4 sv[4];
    __builtin_amdgcn_s_setprio(1);
#pragma unroll
    for (int qtile = 0; qtile < 4; qtile++) {
      f32x4 z = (f32x4){0.f, 0.f, 0.f, 0.f};
      z = __builtin_amdgcn_mfma_f32_16x16x32_bf16(a0, bq[qtile][0], z, 0, 0, 0);
      sv[qtile] =
          __builtin_amdgcn_mfma_f32_16x16x32_bf16(a1, bq[qtile][1], z, 0, 0, 0);
    }
    __builtin_amdgcn_s_setprio(0);

    // causal mask: only the diagonal tile is partial
    if (s0 == qb) {
      const int sgbase = s0 + 16 * w + quad * 4;
#pragma unroll
      for (int qtile = 0; qtile < 4; qtile++) {
        const int qg = qb + qtile * 16 + l16;
#pragma unroll
        for (int reg = 0; reg < 4; reg++)
          if (sgbase + reg > qg) sv[qtile][reg] = -1e30f;
      }
    }

    // p = 2^s, packed IN-LANE: D(16x16x32) layout == B(16x16x16) layout,
    // so bp is directly the PV B-operand. No LDS round-trip.
    short4v bp[4];
#pragma unroll
    for (int qtile = 0; qtile < 4; qtile++) {
      uint2 pk;
      pk.x = pack_bf16x2(exp2f(sv[qtile][0]), exp2f(sv[qtile][1]));
      pk.y = pack_bf16x2(exp2f(sv[qtile][2]), exp2f(sv[qtile][3]));
      bp[qtile] = __builtin_bit_cast(short4v, pk);
    }

    // lsum partial via ones-A: D[m][q] = sum over this wave's 16 keys
#pragma unroll
    for (int qtile = 0; qtile < 4; qtile++)
      lacc[qtile] = __builtin_amdgcn_mfma_f32_16x16x16bf16_1k(
          aones4, bp[qtile], lacc[qtile], 0, 0, 0);

    // O^T partial += V^T[:, k-slice] P^T[k-slice, :]
    const unsigned short* vb = cur ? v1 : v0;
    __builtin_amdgcn_s_setprio(1);
#pragma unroll
    for (int dt = 0; dt < 4; dt++) {
      const short4v av =
          __builtin_bit_cast(short4v, *(const uint2*)(vb + dt * 1024));
#pragma unroll
      for (int qtile = 0; qtile < 4; qtile++)
        o[dt][qtile] = __builtin_amdgcn_mfma_f32_16x16x16bf16_1k(
            av, bp[qtile], o[dt][qtile], 0, 0, 0);
    }
    __builtin_amdgcn_s_setprio(0);
  }

  // ---- end combine (once per block): sum 4 waves' partial O and lsum ----
  // lsum rows are replicated across quad/reg; lane l16 of quad 0 writes.
  if (quad == 0) {
#pragma unroll
    for (int qtile = 0; qtile < 4; qtile++)
      lsumLDS[w][qtile * 16 + l16] = lacc[qtile][0];
  }
  block_barrier();  // all loop LDS reads done; smem reusable; lsum visible

  float* comb = (float*)smem;  // [64 q][68] f32 (padded rows, 17.4KB < 32KB)
#pragma unroll
  for (int ww = 0; ww < 4; ww++) {
    if (w == ww) {
#pragma unroll
      for (int dt = 0; dt < 4; dt++)
#pragma unroll
        for (int qtile = 0; qtile < 4; qtile++) {
          // lane holds (d = dt*16 + quad*4 + reg, q = qtile*16 + l16)
          float* dst = comb + (qtile * 16 + l16) * 68 + dt * 16 + quad * 4;
          if (ww == 0) {
            *(f32x4*)dst = o[dt][qtile];
          } else {
            f32x4 t = *(const f32x4*)dst;
            t += o[dt][qtile];
            *(f32x4*)dst = t;
          }
        }
    }
    block_barrier();
  }

  // read-out: wave w owns q rows [16w,16w+16); lane = row 16w+l16, quad
  // covers d = quad*16 .. +16. Scale by 1/lsum, pack bf16, store.
  const int qloc = 16 * w + l16;
  const float ls = lsumLDS[0][qloc] + lsumLDS[1][qloc] + lsumLDS[2][qloc] +
                   lsumLDS[3][qloc];
  const float invl = 1.0f / ls;
  const float* src = comb + qloc * 68 + quad * 16;
  unsigned short* orow =
      O + (size_t)(qb + qloc) * C_DIM + h * HEAD_D + quad * 16;
#pragma unroll
  for (int j2 = 0; j2 < 4; j2++) {
    const f32x4 t = *(const f32x4*)(src + j2 * 4);
    uint2 pk;
    pk.x = pack_bf16x2(t[0] * invl, t[1] * invl);
    pk.y = pack_bf16x2(t[2] * invl, t[3] * invl);
    *(uint2*)(orow + j2 * 4) = pk;
  }
}

// ---------------------------------------------------------------------------
// Launch (4 kernels: prep -> gemm_qkv_rope -> attn -> gemm_out)
// ---------------------------------------------------------------------------
extern "C" void kernel_launch(void* const* d_in, const int* in_sizes, int n_in,
                              void* d_out, int out_size, void* d_ws,
                              size_t ws_size, hipStream_t stream) {
  const float* x = (const float*)d_in[0];      // [T][C]
  const float* w_qkv = (const float*)d_in[1];  // [C][3C]
  const float* w_out = (const float*)d_in[2];  // [C][C]
  float* out = (float*)d_out;                  // [T][C]

  char* ws = (char*)d_ws;
  // Workspace layout (88 MB peak):
  //   [0, 8MB):   attn_ob bf16 [T][C]
  //   [24,25MB):  cs float2 [T][32] (RoPE cos/sin table)
  //   [48,56MB):  Qb bf16 [H][T][D] (roped, pre-scaled by 0.125*log2e)
  //   [56,64MB):  Kb bf16 [H][T][D] (roped)
  //   [64,72MB):  Vt bf16 [H][D][T]
  //   [72,80MB):  xb bf16 [T][C]
  //   [80,86MB):  wqkvT bf16 [3C][C]
  //   [86,88MB):  woutT bf16 [C][C]
  unsigned short* attn_ob = (unsigned short*)ws;
  float2* cst = (float2*)(ws + (size_t)24 * 1024 * 1024);
  unsigned short* Qb = (unsigned short*)(ws + (size_t)48 * 1024 * 1024);
  unsigned short* Kb = (unsigned short*)(ws + (size_t)56 * 1024 * 1024);
  unsigned short* Vt = (unsigned short*)(ws + (size_t)64 * 1024 * 1024);
  unsigned short* xb = (unsigned short*)(ws + (size_t)72 * 1024 * 1024);
  unsigned short* wqkvT = (unsigned short*)(ws + (size_t)80 * 1024 * 1024);
  unsigned short* woutT = (unsigned short*)(ws + (size_t)86 * 1024 * 1024);

  dim3 blk(256);

  prep_inputs<<<dim3(3104), blk, 0, stream>>>(
      x, w_qkv, w_out, (unsigned int*)xb, (unsigned int*)wqkvT,
      (unsigned int*)woutT, cst);

  gemm_qkv_rope<<<dim3(3072 / 128, T_SEQ / 128), blk, 0, stream>>>(
      xb, wqkvT, cst, Qb, Kb, Vt);

  // flash attention v8: key-slice waves, in-register P, 1024 qmap blocks
  attn_mfma<<<dim3(1024), blk, 0, stream>>>(Qb, Kb, Vt, attn_ob);

  gemm_bt_bf16_64<<<dim3(C_DIM / 64, T_SEQ / 64), blk, 0, stream>>>(
      attn_ob, woutT, out, T_SEQ, C_DIM, C_DIM);
}